// Round 10
// baseline (171.071 us; speedup 1.0000x reference)
//
#include <hip/hip_runtime.h>

// ChannelAttentionBlock: per batch b, F = x[b] viewed as [4096,128] (row-major).
// S = F F^T ; P = softmax rows ; out[b] = F^T P -> [128, 4096].
//
// k0 cab_prep    : Fbb=bf16(x), Ftb=bf16(x)^T, nrm[b][n]=||bf16 F_n||, bmax[512]
// k0b cab_mx     : mxf[b] = max over batch-b block maxes
// k1 cab_rowstats: zpart[mh][b][n] = sum_{m in half} 2^(S*L2E + nsh_n)   (grid 1024)
// k1b cab_c2     : c2[n] = nsh_n - log2(z0+z1)
// k2 cab_out     : recompute S, W = 2^(S*L2E + c2), O += F^T W; SPLIT-K over n
//                  (grid 1024, halves atomically add partial O into zeroed out)
//
// Round-9 lesson: occupancy = min(LDS, VGPR, GRID/CU) -- grid 512 capped at
// 2 blocks/CU regardless of LDS. Split-K raises grid to 1024 -> 3 blocks/CU.
// S bytes/chain order identical in k1/k2 (bit-exact between passes). LDS tiles:
// linear rows, 16B-chunk XOR swizzle (chunk ^ (row&mask)) on gload SOURCE and read.

typedef __attribute__((ext_vector_type(8))) __bf16 bf16x8;
typedef __attribute__((ext_vector_type(4))) float f32x4;
typedef __attribute__((ext_vector_type(4))) unsigned int u32x4;

#define MFMA16(a, b, c) __builtin_amdgcn_mfma_f32_16x16x32_bf16((a), (b), (c), 0, 0, 0)
#define GLOAD16(g, l)                                                       \
  __builtin_amdgcn_global_load_lds(                                         \
      (const __attribute__((address_space(1))) void*)(g),                   \
      (__attribute__((address_space(3))) void*)(l), 16, 0, 0)
#define GLOAD4(g, l)                                                        \
  __builtin_amdgcn_global_load_lds(                                         \
      (const __attribute__((address_space(1))) void*)(g),                   \
      (__attribute__((address_space(3))) void*)(l), 4, 0, 0)

static constexpr int NT = 4096;
static constexpr int DD = 128;
static constexpr float L2E = 1.4426950408889634f;

__device__ __forceinline__ unsigned short bfc(float f) {
  return __builtin_bit_cast(unsigned short, (__bf16)f);
}
__device__ __forceinline__ float bf2f(unsigned short u) {
  return (float)__builtin_bit_cast(__bf16, u);
}

// ---------------------------------------------------------------------------
// k0: fused cast + transpose + row norms. grid 512: b=blk&7, n0=(blk>>3)*64.
// ---------------------------------------------------------------------------
__global__ __launch_bounds__(256) void cab_prep(const float* __restrict__ x,
                                                ushort* __restrict__ Fbb,
                                                ushort* __restrict__ Ftb,
                                                float* __restrict__ nrm,
                                                float* __restrict__ bmax) {
  const int blk = blockIdx.x;
  const int b = blk & 7, n0 = (blk >> 3) * 64;
  const float* F = x + ((size_t)b * NT + n0) * DD;
  ushort* Fo = Fbb + ((size_t)b * NT + n0) * DD;
  ushort* To = Ftb + (size_t)b * DD * NT + n0;

  __shared__ ushort T[128 * 66];  // [d][n] stride 132B (4-aligned, bank-spread)
  __shared__ float redw[4];

  const int t = threadIdx.x, seg = t & 15, rl = t >> 4;
  float lmax = 0.f;

#pragma unroll
  for (int i = 0; i < 4; ++i) {
    const int r = i * 16 + rl;
    float4 u = *(const float4*)(F + (size_t)r * DD + seg * 8);
    float4 v = *(const float4*)(F + (size_t)r * DD + seg * 8 + 4);
    ushort w[8] = {bfc(u.x), bfc(u.y), bfc(u.z), bfc(u.w),
                   bfc(v.x), bfc(v.y), bfc(v.z), bfc(v.w)};
    *(ushort4*)(Fo + (size_t)r * DD + seg * 8) = make_ushort4(w[0], w[1], w[2], w[3]);
    *(ushort4*)(Fo + (size_t)r * DD + seg * 8 + 4) = make_ushort4(w[4], w[5], w[6], w[7]);
    float s = 0.f;
#pragma unroll
    for (int j = 0; j < 8; ++j) {
      T[(seg * 8 + j) * 66 + r] = w[j];
      float f = bf2f(w[j]);
      s = fmaf(f, f, s);
    }
#pragma unroll
    for (int off = 1; off < 16; off <<= 1) s += __shfl_xor(s, off, 64);
    float rn = sqrtf(s);
    if (seg == 0) nrm[(size_t)b * NT + n0 + r] = rn;
    lmax = fmaxf(lmax, rn);
  }
#pragma unroll
  for (int off = 1; off < 64; off <<= 1) lmax = fmaxf(lmax, __shfl_xor(lmax, off, 64));
  if ((t & 63) == 0) redw[t >> 6] = lmax;
  __syncthreads();
  if (t == 0) bmax[blk] = fmaxf(fmaxf(redw[0], redw[1]), fmaxf(redw[2], redw[3]));

  // transpose out: thread (d = idx>>3, ch = idx&7) writes 16B along n
#pragma unroll
  for (int i = 0; i < 4; ++i) {
    int idx = i * 256 + t;
    int d = idx >> 3, ch = idx & 7;
    const ushort* p = &T[d * 66 + ch * 8];
    u32x4 q;
    q[0] = *(const unsigned*)(p + 0);
    q[1] = *(const unsigned*)(p + 2);
    q[2] = *(const unsigned*)(p + 4);
    q[3] = *(const unsigned*)(p + 6);
    *(u32x4*)(To + (size_t)d * NT + ch * 8) = q;
  }
}

// ---------------------------------------------------------------------------
// k0b: per-batch max of block maxes. grid 8 x 64.
// ---------------------------------------------------------------------------
__global__ __launch_bounds__(64) void cab_mx(const float* __restrict__ bmax,
                                             float* __restrict__ mxf) {
  const int b = blockIdx.x, l = threadIdx.x;
  float m = bmax[l * 8 + b];
#pragma unroll
  for (int off = 1; off < 64; off <<= 1) m = fmaxf(m, __shfl_xor(m, off, 64));
  if (l == 0) mxf[b] = m;
}

// ---------------------------------------------------------------------------
// k1: Z partials. grid 1024: b=blk&7, nb=((blk>>3)&63)*64, mh=blk>>9.
// Each block sums 32 m-steps (half the m range). 1 barrier/step.
// ---------------------------------------------------------------------------
__global__ __launch_bounds__(256, 4) void cab_rowstats(const ushort* __restrict__ Fbb,
                                                       const float* __restrict__ nrm,
                                                       const float* __restrict__ mxf,
                                                       float* __restrict__ zpart) {
  const int b = blockIdx.x & 7;
  const int nb = ((blockIdx.x >> 3) & 63) * 64;
  const int mhalf = blockIdx.x >> 9;
  const ushort* Fb = Fbb + (size_t)b * NT * DD;

  const int t = threadIdx.x, lane = t & 63, wv = t >> 6;
  const int lcol = lane & 15, hi = lane >> 4;
  const int nh = wv >> 1, mq = wv & 1;

  __shared__ __align__(16) char FmB[2][16384];  // [64 m][16 chunks], swz ^(m&15)
  __shared__ float zred[64];

  int fmoff[4];
#pragma unroll
  for (int i = 0; i < 4; ++i) {
    int L = i * 256 + t;
    int m = L >> 4, c = (L & 15) ^ (m & 15);
    fmoff[i] = m * DD + c * 8;
  }

  // A fragments: wave's 32 n-rows, registers for whole kernel
  bf16x8 afr[2][4];
#pragma unroll
  for (int nt = 0; nt < 2; ++nt)
#pragma unroll
    for (int ks = 0; ks < 4; ++ks)
      afr[nt][ks] = *(const bf16x8*)(Fb + (size_t)(nb + nh * 32 + nt * 16 + lcol) * DD +
                                     ks * 32 + hi * 8);

  // negated Cauchy-Schwarz shift (log2 units)
  const float mxv = mxf[b] * L2E;
  float nsh[8];
#pragma unroll
  for (int nt = 0; nt < 2; ++nt)
#pragma unroll
    for (int r = 0; r < 4; ++r)
      nsh[nt * 4 + r] = -nrm[(size_t)b * NT + nb + nh * 32 + nt * 16 + hi * 4 + r] * mxv;

  const ushort* Fm0 = Fb + (size_t)mhalf * 2048 * DD;
  // prologue
#pragma unroll
  for (int i = 0; i < 4; ++i) GLOAD16(Fm0 + fmoff[i], &FmB[0][i * 4096 + wv * 1024]);
  __syncthreads();

  float zloc[8];
#pragma unroll
  for (int i = 0; i < 8; ++i) zloc[i] = 0.f;

  for (int s = 0; s < 32; ++s) {
    const int cur = s & 1;
    if (s < 31) {
      const ushort* src = Fm0 + (size_t)(s + 1) * 64 * DD;
#pragma unroll
      for (int i = 0; i < 4; ++i)
        GLOAD16(src + fmoff[i], &FmB[cur ^ 1][i * 4096 + wv * 1024]);
    }

    f32x4 sacc[2][2];
#pragma unroll
    for (int nt = 0; nt < 2; ++nt)
#pragma unroll
      for (int ms = 0; ms < 2; ++ms) sacc[nt][ms] = (f32x4){0.f, 0.f, 0.f, 0.f};
#pragma unroll
    for (int ms = 0; ms < 2; ++ms)
#pragma unroll
      for (int ks = 0; ks < 4; ++ks) {
        int ml = mq * 32 + ms * 16 + lcol;
        bf16x8 bb = *(const bf16x8*)&FmB[cur][ml * 256 + (((ks * 4 + hi) ^ lcol) << 4)];
#pragma unroll
        for (int nt = 0; nt < 2; ++nt) sacc[nt][ms] = MFMA16(afr[nt][ks], bb, sacc[nt][ms]);
      }
#pragma unroll
    for (int nt = 0; nt < 2; ++nt)
#pragma unroll
      for (int r = 0; r < 4; ++r)
        zloc[nt * 4 + r] += __builtin_amdgcn_exp2f(fmaf(sacc[nt][0][r], L2E, nsh[nt * 4 + r])) +
                            __builtin_amdgcn_exp2f(fmaf(sacc[nt][1][r], L2E, nsh[nt * 4 + r]));
    __syncthreads();
  }

  // reduce over the 16 m-cols
#pragma unroll
  for (int i = 0; i < 8; ++i) {
#pragma unroll
    for (int off = 1; off < 16; off <<= 1) zloc[i] += __shfl_xor(zloc[i], off, 64);
  }
  if (mq == 1 && lcol == 0) {
#pragma unroll
    for (int i = 0; i < 8; ++i) zred[nh * 32 + (i >> 2) * 16 + hi * 4 + (i & 3)] = zloc[i];
  }
  __syncthreads();
  if (mq == 0 && lcol == 0) {
#pragma unroll
    for (int i = 0; i < 8; ++i) {
      int nloc = nh * 32 + (i >> 2) * 16 + hi * 4 + (i & 3);
      zpart[(size_t)mhalf * 8 * NT + (size_t)b * NT + nb + nloc] = zloc[i] + zred[nloc];
    }
  }
}

// ---------------------------------------------------------------------------
// k1b: combine Z halves -> c2. grid 128. (same nsh formula as k1, exact ops)
// ---------------------------------------------------------------------------
__global__ __launch_bounds__(256) void cab_c2(const float* __restrict__ zpart,
                                              const float* __restrict__ nrm,
                                              const float* __restrict__ mxf,
                                              float* __restrict__ c2g) {
  int i = blockIdx.x * 256 + threadIdx.x;
  int b = i >> 12;
  float z = zpart[i] + zpart[8 * NT + i];
  float nsh = -nrm[i] * (mxf[b] * L2E);
  c2g[i] = nsh - __log2f(z);
}

// ---------------------------------------------------------------------------
// k2: O += F^T W (split-K). grid 1024: b=blk&7, mb0=((blk>>3)&63)*64, half=blk>>9.
// Each block: 32 n-steps, then atomically adds its partial [128 d][64 m] tile.
// 42.5 KB LDS, single-buffered FnB/FttB, 2 barriers/step (v9 schedule).
// ---------------------------------------------------------------------------
__global__ __launch_bounds__(256, 2) void cab_out(const ushort* __restrict__ Fbb,
                                                  const ushort* __restrict__ Ftb,
                                                  const float* __restrict__ c2g,
                                                  float* __restrict__ out) {
  const int b = blockIdx.x & 7, mb0 = ((blockIdx.x >> 3) & 63) * 64;
  const int s0 = (blockIdx.x >> 9) * 32, s1 = s0 + 32;
  const ushort* Fb = Fbb + (size_t)b * NT * DD;
  const ushort* Ft = Ftb + (size_t)b * DD * NT;
  const float* c2p = c2g + (size_t)b * NT;

  const int t = threadIdx.x, lane = t & 63, wv = t >> 6;
  const int lcol = lane & 15, hi = lane >> 4;
  const int mh = wv & 1, nh = wv >> 1;

  // 42496 B total: FnB 16K | FttB 16K | Wt 9216 | c2l 512
  __shared__ __align__(16) char LB[42496];
  char* FnB = LB;                     // [64 n][16 chunks], swz ^(n&15) (single buf)
  char* FttB = LB + 16384;            // [128 d][8 chunks], swz ^(d&7)  (single buf)
  char* Wt = LB + 32768;              // 4 x [32 m][72 B] wave-private
  float* c2l = (float*)(LB + 41984);  // [2][64]

  int fnoff[4], fttoff[4];
#pragma unroll
  for (int i = 0; i < 4; ++i) {
    int L = i * 256 + t;
    int n = L >> 4, cn = (L & 15) ^ (n & 15);
    fnoff[i] = n * DD + cn * 8;
    int d = L >> 3, cd = (L & 7) ^ (d & 7);
    fttoff[i] = d * NT + cd * 8;
  }

  // G1 B-operand: wave's 32 m-rows in registers
  bf16x8 fmf[2][4];
#pragma unroll
  for (int ms = 0; ms < 2; ++ms)
#pragma unroll
    for (int ks = 0; ks < 4; ++ks)
      fmf[ms][ks] = *(const bf16x8*)(Fb + (size_t)(mb0 + mh * 32 + ms * 16 + lcol) * DD +
                                     ks * 32 + hi * 8);

  f32x4 accO[8][2];  // [dt][msub]
#pragma unroll
  for (int dt = 0; dt < 8; ++dt)
#pragma unroll
    for (int ms = 0; ms < 2; ++ms) accO[dt][ms] = (f32x4){0.f, 0.f, 0.f, 0.f};

  // prologue: stage step s0
#pragma unroll
  for (int i = 0; i < 4; ++i)
    GLOAD16(Fb + (size_t)s0 * 64 * DD + fnoff[i], &FnB[i * 4096 + wv * 1024]);
#pragma unroll
  for (int i = 0; i < 4; ++i)
    GLOAD16(Ft + s0 * 64 + fttoff[i], &FttB[i * 4096 + wv * 1024]);
  if (wv == 0) GLOAD4(c2p + s0 * 64 + lane, &c2l[(s0 & 1) * 64]);
  __syncthreads();

  const unsigned wtbase = wv * 2304;

  for (int s = s0; s < s1; ++s) {
    // --- phase 1: all tile reads (before overwrite) ---
    f32x4 sacc[2][2];  // [nt][msub]
#pragma unroll
    for (int nt = 0; nt < 2; ++nt)
#pragma unroll
      for (int ms = 0; ms < 2; ++ms) sacc[nt][ms] = (f32x4){0.f, 0.f, 0.f, 0.f};
#pragma unroll
    for (int nt = 0; nt < 2; ++nt)
#pragma unroll
      for (int ks = 0; ks < 4; ++ks) {
        int n = (nh * 2 + nt) * 16 + lcol;
        bf16x8 a = *(const bf16x8*)&FnB[n * 256 + (((ks * 4 + hi) ^ lcol) << 4)];
#pragma unroll
        for (int ms = 0; ms < 2; ++ms) sacc[nt][ms] = MFMA16(a, fmf[ms][ks], sacc[nt][ms]);
      }
    // G2 A-frags into registers (must precede the DMA overwrite)
    bf16x8 a2[8];
#pragma unroll
    for (int dt = 0; dt < 8; ++dt)
      a2[dt] = *(const bf16x8*)&FttB[(dt * 16 + lcol) * 128 +
                                     (((nh * 4 + hi) ^ (lcol & 7)) << 4)];

    __syncthreads();  // #1: all FnB/FttB reads complete

    // --- phase 2: issue next-step DMA into the (now free) single buffers ---
    if (s < s1 - 1) {
      const ushort* fs = Fb + (size_t)(s + 1) * 64 * DD;
      const ushort* ts = Ft + (s + 1) * 64;
#pragma unroll
      for (int i = 0; i < 4; ++i) GLOAD16(fs + fnoff[i], &FnB[i * 4096 + wv * 1024]);
#pragma unroll
      for (int i = 0; i < 4; ++i) GLOAD16(ts + fttoff[i], &FttB[i * 4096 + wv * 1024]);
      if (wv == 0) GLOAD4(c2p + (s + 1) * 64 + lane, &c2l[((s + 1) & 1) * 64]);
    }

    // --- phase 3: W build + G2 (register/W-LDS only; overlaps DMA) ---
#pragma unroll
    for (int nt = 0; nt < 2; ++nt) {
      float4 cv = *(const float4*)&c2l[(s & 1) * 64 + nh * 32 + nt * 16 + hi * 4];
#pragma unroll
      for (int ms = 0; ms < 2; ++ms) {
        ushort4 wp;
        wp.x = bfc(__builtin_amdgcn_exp2f(fmaf(sacc[nt][ms][0], L2E, cv.x)));
        wp.y = bfc(__builtin_amdgcn_exp2f(fmaf(sacc[nt][ms][1], L2E, cv.y)));
        wp.z = bfc(__builtin_amdgcn_exp2f(fmaf(sacc[nt][ms][2], L2E, cv.z)));
        wp.w = bfc(__builtin_amdgcn_exp2f(fmaf(sacc[nt][ms][3], L2E, cv.w)));
        *(ushort4*)&Wt[wtbase + (ms * 16 + lcol) * 72 + nt * 32 + hi * 8] = wp;
      }
    }
    bf16x8 b2[2];
#pragma unroll
    for (int ms = 0; ms < 2; ++ms) {
      const char* p = &Wt[wtbase + (ms * 16 + lcol) * 72 + hi * 16];
      uint2 lo = *(const uint2*)p;
      uint2 h2 = *(const uint2*)(p + 8);
      b2[ms] = __builtin_bit_cast(bf16x8, (u32x4){lo.x, lo.y, h2.x, h2.y});
    }
#pragma unroll
    for (int dt = 0; dt < 8; ++dt)
#pragma unroll
      for (int ms = 0; ms < 2; ++ms) accO[dt][ms] = MFMA16(a2[dt], b2[ms], accO[dt][ms]);

    __syncthreads();  // #2: drains DMA (vmcnt 0) -> next step's tiles ready
  }

  // epilogue: sum nh-partials via LDS, then ATOMIC-ADD the half-tile into out
  float* red = (float*)LB;
  if (nh == 1) {
#pragma unroll
    for (int dt = 0; dt < 8; ++dt)
#pragma unroll
      for (int ms = 0; ms < 2; ++ms)
#pragma unroll
        for (int r = 0; r < 4; ++r)
          red[mh * 4096 + (dt * 8 + ms * 4 + r) * 64 + lane] = accO[dt][ms][r];
  }
  __syncthreads();
  if (nh == 0) {
    float* Ob = out + (size_t)b * DD * NT;
#pragma unroll
    for (int dt = 0; dt < 8; ++dt)
#pragma unroll
      for (int ms = 0; ms < 2; ++ms)
#pragma unroll
        for (int r = 0; r < 4; ++r) {
          float v = accO[dt][ms][r] + red[mh * 4096 + (dt * 8 + ms * 4 + r) * 64 + lane];
          atomicAdd(&Ob[(size_t)(dt * 16 + hi * 4 + r) * NT + mb0 + mh * 32 + ms * 16 + lcol], v);
        }
  }
}

extern "C" void kernel_launch(void* const* d_in, const int* in_sizes, int n_in,
                              void* d_out, int out_size, void* d_ws, size_t ws_size,
                              hipStream_t stream) {
  const float* x = (const float*)d_in[0];
  float* out = (float*)d_out;
  char* ws = (char*)d_ws;
  ushort* Fbb = (ushort*)ws;                          // 8 MB
  ushort* Ftb = (ushort*)(ws + (8u << 20));           // 8 MB
  float* nrm = (float*)(ws + (16u << 20));            // 128 KB
  float* bmax = (float*)(ws + (16u << 20) + 131072);  // 2 KB
  float* mxf = (float*)(ws + (16u << 20) + 133120);   // 32 B (pad to 1 KB)
  float* c2 = (float*)(ws + (16u << 20) + 134144);    // 128 KB
  float* zpart = (float*)(ws + (16u << 20) + 265216); // 256 KB

  // zero the output (split-K halves accumulate atomically; graph-capturable)
  hipMemsetAsync(out, 0, (size_t)out_size * sizeof(float), stream);

  hipLaunchKernelGGL(cab_prep, dim3(512), dim3(256), 0, stream, x, Fbb, Ftb, nrm, bmax);
  hipLaunchKernelGGL(cab_mx, dim3(8), dim3(64), 0, stream, bmax, mxf);
  hipLaunchKernelGGL(cab_rowstats, dim3(1024), dim3(256), 0, stream, Fbb, nrm, mxf, zpart);
  hipLaunchKernelGGL(cab_c2, dim3(128), dim3(256), 0, stream, zpart, nrm, mxf, c2);
  hipLaunchKernelGGL(cab_out, dim3(1024), dim3(256), 0, stream, Fbb, Ftb, c2, out);
}

// Round 11
// 132.106 us; speedup vs baseline: 1.2950x; 1.2950x over previous
//
#include <hip/hip_runtime.h>

// ChannelAttentionBlock: per batch b, F = x[b] viewed as [4096,128] (row-major).
// S = F F^T ; P = softmax rows ; out[b] = F^T P -> [128, 4096].
//
// k0 cab_prep    : Fbb=bf16(x); FtFrag = fragment-major F^T (per (s,nh,dt) chunk,
//                  lane's 16B = the exact G2 MFMA A-fragment); nrm; bmax.
// k0b cab_mx     : mxf[b] = max over batch-b block maxes
// k1 cab_rowstats: c2[n] = nsh_n - log2 sum_m 2^(S*L2E + nsh_n),
//                  nsh_n = -nrm_n*mx_b*L2E (Cauchy-Schwarz shift, no online max)
// k2 cab_out     : recompute S, W = 2^(S*L2E + c2) (wave-private LDS), O += F^T W
//                  G2 A-frags = coalesced 16B/lane loads from L2-resident FtFrag
//                  (v11: removes FttB -> LDS traffic 112K->64K per block-step;
//                   round-8 lesson: global A is fine IFF per-lane addrs coalesce;
//                   round-9/10 lesson: kernel is LDS-pipe-bound, not occupancy).
//
// S bytes/chain order identical in k1/k2 (bit-exact between passes). LDS tiles:
// linear rows, 16B-chunk XOR swizzle (chunk ^ (row&15)) on gload SOURCE and read.

typedef __attribute__((ext_vector_type(8))) __bf16 bf16x8;
typedef __attribute__((ext_vector_type(4))) float f32x4;
typedef __attribute__((ext_vector_type(4))) unsigned int u32x4;

#define MFMA16(a, b, c) __builtin_amdgcn_mfma_f32_16x16x32_bf16((a), (b), (c), 0, 0, 0)
#define GLOAD16(g, l)                                                       \
  __builtin_amdgcn_global_load_lds(                                         \
      (const __attribute__((address_space(1))) void*)(g),                   \
      (__attribute__((address_space(3))) void*)(l), 16, 0, 0)
#define GLOAD4(g, l)                                                        \
  __builtin_amdgcn_global_load_lds(                                         \
      (const __attribute__((address_space(1))) void*)(g),                   \
      (__attribute__((address_space(3))) void*)(l), 4, 0, 0)

static constexpr int NT = 4096;
static constexpr int DD = 128;
static constexpr float L2E = 1.4426950408889634f;

__device__ __forceinline__ unsigned short bfc(float f) {
  return __builtin_bit_cast(unsigned short, (__bf16)f);
}
__device__ __forceinline__ float bf2f(unsigned short u) {
  return (float)__builtin_bit_cast(__bf16, u);
}

// ---------------------------------------------------------------------------
// k0: fused cast + fragment-transpose + row norms. grid 512: b=blk&7, n0-block.
// FtFrag layout (per batch, 1 MB): chunk = (s*2 + nh)*8 + dt  (s = n-step),
//   chunk holds 64 lanes x 16B; lane l covers d = dt*16 + (l&15),
//   n = s*64 + nh*32 + (l>>4)*8 + j, j=0..7.
// ---------------------------------------------------------------------------
__global__ __launch_bounds__(256) void cab_prep(const float* __restrict__ x,
                                                ushort* __restrict__ Fbb,
                                                ushort* __restrict__ FtF,
                                                float* __restrict__ nrm,
                                                float* __restrict__ bmax) {
  const int blk = blockIdx.x;
  const int b = blk & 7, n0 = (blk >> 3) * 64;
  const float* F = x + ((size_t)b * NT + n0) * DD;
  ushort* Fo = Fbb + ((size_t)b * NT + n0) * DD;
  ushort* To = FtF + (size_t)b * DD * NT;

  __shared__ ushort T[128 * 68];  // [d][n-local], stride 136 B (8B-aligned rows)
  __shared__ float redw[4];

  const int t = threadIdx.x, seg = t & 15, rl = t >> 4;
  float lmax = 0.f;

#pragma unroll
  for (int i = 0; i < 4; ++i) {
    const int r = i * 16 + rl;
    float4 u = *(const float4*)(F + (size_t)r * DD + seg * 8);
    float4 v = *(const float4*)(F + (size_t)r * DD + seg * 8 + 4);
    ushort w[8] = {bfc(u.x), bfc(u.y), bfc(u.z), bfc(u.w),
                   bfc(v.x), bfc(v.y), bfc(v.z), bfc(v.w)};
    *(ushort4*)(Fo + (size_t)r * DD + seg * 8) = make_ushort4(w[0], w[1], w[2], w[3]);
    *(ushort4*)(Fo + (size_t)r * DD + seg * 8 + 4) = make_ushort4(w[4], w[5], w[6], w[7]);
    float s = 0.f;
#pragma unroll
    for (int j = 0; j < 8; ++j) {
      T[(seg * 8 + j) * 68 + r] = w[j];
      float f = bf2f(w[j]);
      s = fmaf(f, f, s);
    }
#pragma unroll
    for (int off = 1; off < 16; off <<= 1) s += __shfl_xor(s, off, 64);
    float rn = sqrtf(s);
    if (seg == 0) nrm[(size_t)b * NT + n0 + r] = rn;
    lmax = fmaxf(lmax, rn);
  }
#pragma unroll
  for (int off = 1; off < 64; off <<= 1) lmax = fmaxf(lmax, __shfl_xor(lmax, off, 64));
  if ((t & 63) == 0) redw[t >> 6] = lmax;
  __syncthreads();
  if (t == 0) bmax[blk] = fmaxf(fmaxf(redw[0], redw[1]), fmaxf(redw[2], redw[3]));

  // fragment-transpose out: idx -> (nh = idx>>9, dt = (idx>>6)&7, ln = idx&63)
#pragma unroll
  for (int i = 0; i < 4; ++i) {
    int idx = i * 256 + t;
    int nh = idx >> 9, dt = (idx >> 6) & 7, ln = idx & 63;
    int d = dt * 16 + (ln & 15), nl = nh * 32 + (ln >> 4) * 8;
    const ushort* p = &T[d * 68 + nl];
    uint2 q0 = *(const uint2*)p;        // 8B-aligned (136d%16 in {0,8}, 2nl%16==0)
    uint2 q1 = *(const uint2*)(p + 4);
    u32x4 q = {q0.x, q0.y, q1.x, q1.y};
    *(u32x4*)(To + (size_t)(((n0 >> 6) * 2 + nh) * 8 + dt) * 512 + ln * 8) = q;
  }
}

// ---------------------------------------------------------------------------
// k0b: per-batch max of block maxes. grid 8 x 64.
// ---------------------------------------------------------------------------
__global__ __launch_bounds__(64) void cab_mx(const float* __restrict__ bmax,
                                             float* __restrict__ mxf) {
  const int b = blockIdx.x, l = threadIdx.x;
  float m = bmax[l * 8 + b];
#pragma unroll
  for (int off = 1; off < 64; off <<= 1) m = fmaxf(m, __shfl_xor(m, off, 64));
  if (l == 0) mxf[b] = m;
}

// ---------------------------------------------------------------------------
// k1: c2 stats. grid 512: b=blk&7, nb=(blk>>3)*64. Full-m pass, 1 barrier/step.
// (round-7 verbatim — measured good)
// ---------------------------------------------------------------------------
__global__ __launch_bounds__(256, 4) void cab_rowstats(const ushort* __restrict__ Fbb,
                                                       const float* __restrict__ nrm,
                                                       const float* __restrict__ mxf,
                                                       float* __restrict__ c2g) {
  const int b = blockIdx.x & 7;
  const int nb = (blockIdx.x >> 3) * 64;
  const ushort* Fb = Fbb + (size_t)b * NT * DD;

  const int t = threadIdx.x, lane = t & 63, wv = t >> 6;
  const int lcol = lane & 15, hi = lane >> 4;
  const int nh = wv >> 1, mq = wv & 1;

  __shared__ __align__(16) char FmB[2][16384];  // [64 m][16 chunks], swz ^(m&15)
  __shared__ float zred[64];

  int fmoff[4];
#pragma unroll
  for (int i = 0; i < 4; ++i) {
    int L = i * 256 + t;
    int m = L >> 4, c = (L & 15) ^ (m & 15);
    fmoff[i] = m * DD + c * 8;
  }

  // A fragments: wave's 32 n-rows, registers for whole kernel
  bf16x8 afr[2][4];
#pragma unroll
  for (int nt = 0; nt < 2; ++nt)
#pragma unroll
    for (int ks = 0; ks < 4; ++ks)
      afr[nt][ks] = *(const bf16x8*)(Fb + (size_t)(nb + nh * 32 + nt * 16 + lcol) * DD +
                                     ks * 32 + hi * 8);

  // negated Cauchy-Schwarz shift (log2 units)
  const float mxv = mxf[b] * L2E;
  float nsh[8];
#pragma unroll
  for (int nt = 0; nt < 2; ++nt)
#pragma unroll
    for (int r = 0; r < 4; ++r)
      nsh[nt * 4 + r] = -nrm[(size_t)b * NT + nb + nh * 32 + nt * 16 + hi * 4 + r] * mxv;

  // prologue
#pragma unroll
  for (int i = 0; i < 4; ++i) GLOAD16(Fb + fmoff[i], &FmB[0][i * 4096 + wv * 1024]);
  __syncthreads();

  float zloc[8];
#pragma unroll
  for (int i = 0; i < 8; ++i) zloc[i] = 0.f;

  for (int s = 0; s < 64; ++s) {
    const int cur = s & 1;
    if (s < 63) {
      const ushort* src = Fb + (size_t)(s + 1) * 64 * DD;
#pragma unroll
      for (int i = 0; i < 4; ++i)
        GLOAD16(src + fmoff[i], &FmB[cur ^ 1][i * 4096 + wv * 1024]);
    }

    f32x4 sacc[2][2];
#pragma unroll
    for (int nt = 0; nt < 2; ++nt)
#pragma unroll
      for (int ms = 0; ms < 2; ++ms) sacc[nt][ms] = (f32x4){0.f, 0.f, 0.f, 0.f};
#pragma unroll
    for (int ms = 0; ms < 2; ++ms)
#pragma unroll
      for (int ks = 0; ks < 4; ++ks) {
        int ml = mq * 32 + ms * 16 + lcol;
        bf16x8 bb = *(const bf16x8*)&FmB[cur][ml * 256 + (((ks * 4 + hi) ^ lcol) << 4)];
#pragma unroll
        for (int nt = 0; nt < 2; ++nt) sacc[nt][ms] = MFMA16(afr[nt][ks], bb, sacc[nt][ms]);
      }
#pragma unroll
    for (int nt = 0; nt < 2; ++nt)
#pragma unroll
      for (int r = 0; r < 4; ++r)
        zloc[nt * 4 + r] += __builtin_amdgcn_exp2f(fmaf(sacc[nt][0][r], L2E, nsh[nt * 4 + r])) +
                            __builtin_amdgcn_exp2f(fmaf(sacc[nt][1][r], L2E, nsh[nt * 4 + r]));
    __syncthreads();
  }

  // reduce over the 16 m-cols
#pragma unroll
  for (int i = 0; i < 8; ++i) {
#pragma unroll
    for (int off = 1; off < 16; off <<= 1) zloc[i] += __shfl_xor(zloc[i], off, 64);
  }
  if (mq == 1 && lcol == 0) {
#pragma unroll
    for (int i = 0; i < 8; ++i) zred[nh * 32 + (i >> 2) * 16 + hi * 4 + (i & 3)] = zloc[i];
  }
  __syncthreads();
  if (mq == 0 && lcol == 0) {
#pragma unroll
    for (int i = 0; i < 8; ++i) {
      int nloc = nh * 32 + (i >> 2) * 16 + hi * 4 + (i & 3);
      c2g[(size_t)b * NT + nb + nloc] = nsh[i] - __log2f(zloc[i] + zred[nloc]);
    }
  }
}

// ---------------------------------------------------------------------------
// k2: O = F^T W. grid 512: b=blk&7, mb0=(blk>>3)*64. 42.5 KB LDS.
// Wave (mh=wv&1, nh=wv>>1): 32 m x 32 n per step; fmf in regs; W wave-private;
// double-buffered FnB, 1 barrier/step (round-7 schedule); G2 A-frags =
// coalesced 16B/lane global loads from FtFrag (L2-resident, issued at step top).
// ---------------------------------------------------------------------------
__global__ __launch_bounds__(256, 2) void cab_out(const ushort* __restrict__ Fbb,
                                                  const ushort* __restrict__ FtF,
                                                  const float* __restrict__ c2g,
                                                  float* __restrict__ out) {
  const int b = blockIdx.x & 7, mb0 = (blockIdx.x >> 3) * 64;
  const ushort* Fb = Fbb + (size_t)b * NT * DD;
  const ushort* Fr = FtF + (size_t)b * DD * NT;
  const float* c2p = c2g + (size_t)b * NT;

  const int t = threadIdx.x, lane = t & 63, wv = t >> 6;
  const int lcol = lane & 15, hi = lane >> 4;
  const int mh = wv & 1, nh = wv >> 1;

  // 42496 B: FnB 2x16K | Wt 9216 | c2l 512
  __shared__ __align__(16) char LB[42496];
  char* FnB = LB;                     // [64 n][16 chunks], swz ^(n&15), double buf
  char* Wt = LB + 32768;              // 4 x [32 m][72 B] wave-private
  float* c2l = (float*)(LB + 41984);  // [2][64]

  int fnoff[4];
#pragma unroll
  for (int i = 0; i < 4; ++i) {
    int L = i * 256 + t;
    int n = L >> 4, cn = (L & 15) ^ (n & 15);
    fnoff[i] = n * DD + cn * 8;
  }

  // G1 B-operand: wave's 32 m-rows in registers
  bf16x8 fmf[2][4];
#pragma unroll
  for (int ms = 0; ms < 2; ++ms)
#pragma unroll
    for (int ks = 0; ks < 4; ++ks)
      fmf[ms][ks] = *(const bf16x8*)(Fb + (size_t)(mb0 + mh * 32 + ms * 16 + lcol) * DD +
                                     ks * 32 + hi * 8);

  f32x4 accO[8][2];  // [dt][msub]
#pragma unroll
  for (int dt = 0; dt < 8; ++dt)
#pragma unroll
    for (int ms = 0; ms < 2; ++ms) accO[dt][ms] = (f32x4){0.f, 0.f, 0.f, 0.f};

  // prologue: stage step 0
#pragma unroll
  for (int i = 0; i < 4; ++i) GLOAD16(Fb + fnoff[i], &FnB[i * 4096 + wv * 1024]);
  if (wv == 0) GLOAD4(c2p + lane, &c2l[0]);
  __syncthreads();

  const unsigned wtbase = wv * 2304;
  // FtFrag: this wave's per-step base (chunk = (s*2+nh)*8 + dt, 512 ushorts each)
  const ushort* a2w = Fr + (size_t)(nh * 8) * 512 + lane * 8;

  for (int s = 0; s < 64; ++s) {
    const int cur = s & 1;

    // G2 A-frags from L2 (fully coalesced: 16B/lane, 1KB/wave-instr)
    const ushort* ap = a2w + (size_t)s * 8192;
    bf16x8 a2[8];
#pragma unroll
    for (int dt = 0; dt < 8; ++dt) a2[dt] = *(const bf16x8*)(ap + dt * 512);

    // DMA next step
    if (s < 63) {
      const ushort* fs = Fb + (size_t)(s + 1) * 64 * DD;
#pragma unroll
      for (int i = 0; i < 4; ++i)
        GLOAD16(fs + fnoff[i], &FnB[(cur ^ 1) * 16384 + i * 4096 + wv * 1024]);
      if (wv == 0) GLOAD4(c2p + (s + 1) * 64 + lane, &c2l[((s + 1) & 1) * 64]);
    }

    // G1: S[wave's 32 n][wave's 32 m]; chain identical to k1 -> same S
    f32x4 sacc[2][2];  // [nt][msub]
#pragma unroll
    for (int nt = 0; nt < 2; ++nt)
#pragma unroll
      for (int ms = 0; ms < 2; ++ms) sacc[nt][ms] = (f32x4){0.f, 0.f, 0.f, 0.f};
#pragma unroll
    for (int nt = 0; nt < 2; ++nt)
#pragma unroll
      for (int ks = 0; ks < 4; ++ks) {
        int n = (nh * 2 + nt) * 16 + lcol;
        bf16x8 a = *(const bf16x8*)&FnB[cur * 16384 + n * 256 +
                                        (((ks * 4 + hi) ^ lcol) << 4)];
#pragma unroll
        for (int ms = 0; ms < 2; ++ms) sacc[nt][ms] = MFMA16(a, fmf[ms][ks], sacc[nt][ms]);
      }

    // W = 2^(S*L2E + c2) -> wave-private Wt [32 m][72 B rows]
#pragma unroll
    for (int nt = 0; nt < 2; ++nt) {
      float4 cv = *(const float4*)&c2l[(s & 1) * 64 + nh * 32 + nt * 16 + hi * 4];
#pragma unroll
      for (int ms = 0; ms < 2; ++ms) {
        ushort4 wp;
        wp.x = bfc(__builtin_amdgcn_exp2f(fmaf(sacc[nt][ms][0], L2E, cv.x)));
        wp.y = bfc(__builtin_amdgcn_exp2f(fmaf(sacc[nt][ms][1], L2E, cv.y)));
        wp.z = bfc(__builtin_amdgcn_exp2f(fmaf(sacc[nt][ms][2], L2E, cv.z)));
        wp.w = bfc(__builtin_amdgcn_exp2f(fmaf(sacc[nt][ms][3], L2E, cv.w)));
        *(ushort4*)&Wt[wtbase + (ms * 16 + lcol) * 72 + nt * 32 + hi * 8] = wp;
      }
    }

    // G2: accO[dt][ms] += A2(FtFrag regs) x Wt(B)  (same-wave LDS dep only)
    bf16x8 b2[2];
#pragma unroll
    for (int ms = 0; ms < 2; ++ms) {
      const char* p = &Wt[wtbase + (ms * 16 + lcol) * 72 + hi * 16];
      uint2 lo = *(const uint2*)p;
      uint2 h2 = *(const uint2*)(p + 8);
      b2[ms] = __builtin_bit_cast(bf16x8, (u32x4){lo.x, lo.y, h2.x, h2.y});
    }
#pragma unroll
    for (int dt = 0; dt < 8; ++dt)
#pragma unroll
      for (int ms = 0; ms < 2; ++ms) accO[dt][ms] = MFMA16(a2[dt], b2[ms], accO[dt][ms]);

    __syncthreads();  // drain DMA, flip buffers (only barrier in the step)
  }

  // epilogue: sum nh-partials via LDS (FnB = 32 KB scratch), store f32
  float* red = (float*)LB;
  if (nh == 1) {
#pragma unroll
    for (int dt = 0; dt < 8; ++dt)
#pragma unroll
      for (int ms = 0; ms < 2; ++ms)
#pragma unroll
        for (int r = 0; r < 4; ++r)
          red[mh * 4096 + (dt * 8 + ms * 4 + r) * 64 + lane] = accO[dt][ms][r];
  }
  __syncthreads();
  if (nh == 0) {
    float* Ob = out + (size_t)b * DD * NT;
#pragma unroll
    for (int dt = 0; dt < 8; ++dt)
#pragma unroll
      for (int ms = 0; ms < 2; ++ms)
#pragma unroll
        for (int r = 0; r < 4; ++r) {
          float v = accO[dt][ms][r] + red[mh * 4096 + (dt * 8 + ms * 4 + r) * 64 + lane];
          Ob[(size_t)(dt * 16 + hi * 4 + r) * NT + mb0 + mh * 32 + ms * 16 + lcol] = v;
        }
  }
}

extern "C" void kernel_launch(void* const* d_in, const int* in_sizes, int n_in,
                              void* d_out, int out_size, void* d_ws, size_t ws_size,
                              hipStream_t stream) {
  const float* x = (const float*)d_in[0];
  float* out = (float*)d_out;
  char* ws = (char*)d_ws;
  ushort* Fbb = (ushort*)ws;                         // 8 MB
  ushort* FtF = (ushort*)(ws + (8u << 20));          // 8 MB (fragment-major F^T)
  float* nrm = (float*)(ws + (16u << 20));           // 128 KB
  float* bmax = (float*)(ws + (16u << 20) + 131072); // 2 KB
  float* mxf = (float*)(ws + (16u << 20) + 133120);  // 32 B (pad to 1 KB)
  float* c2 = (float*)(ws + (16u << 20) + 134144);   // 128 KB

  hipLaunchKernelGGL(cab_prep, dim3(512), dim3(256), 0, stream, x, Fbb, FtF, nrm, bmax);
  hipLaunchKernelGGL(cab_mx, dim3(8), dim3(64), 0, stream, bmax, mxf);
  hipLaunchKernelGGL(cab_rowstats, dim3(512), dim3(256), 0, stream, Fbb, nrm, mxf, c2);
  hipLaunchKernelGGL(cab_out, dim3(512), dim3(256), 0, stream, Fbb, FtF, c2, out);
}